// Round 3
// baseline (10445.425 us; speedup 1.0000x reference)
//
#include <hip/hip_runtime.h>
#include <stdint.h>

typedef __bf16 bf16x8 __attribute__((ext_vector_type(8)));
typedef float  f32x4  __attribute__((ext_vector_type(4)));

#define YSZ 33554432ull   // 32*512*2048 output elements

// workspace layout (bytes)
#define R1L_OFF 0ull
#define R2L_OFF 12582912ull
#define W2L_OFF 25165824ull
#define HR1_OFF 37748736ull   // 2 dirs * 16 slots * 64KB
#define HR2_OFF 39845888ull
#define FLG_OFF 41943040ull
#define WS_NEED 41947136ull

// LDS layout (bytes)
#define SM_RECW 0         // 96KB: R1 (A) or R2 (C) slice, B-frag layout
#define SM_XWH  98304     // 32KB: W2 h-gate slice (C only)
#define SM_RED0 131072    // 4KB reduce buf mt0
#define SM_RED1 135168    // 4KB reduce buf mt1
#define SM_HST  139264    // 1KB h staging (32x16 bf16)
#define SM_BYTES 140288

__device__ __forceinline__ unsigned short f2bf(float x){
  unsigned u; __builtin_memcpy(&u, &x, 4);
  u = (u + 0x7fffu + ((u >> 16) & 1u)) >> 16;
  return (unsigned short)u;
}
__device__ __forceinline__ f32x4 mfma16(bf16x8 a, bf16x8 b, f32x4 c){
  return __builtin_amdgcn_mfma_f32_16x16x32_bf16(a, b, c, 0, 0, 0);
}

// ---------------- weight prep: fp32 -> bf16 in MFMA B-frag slice layout ----------------
// regions: 0=R1, 1=R2, 2=W2; within: [dir][idx(64)][g(3)][kt(32)][lane(64)][j(8)]
// col = g*1024 + idx*16 + (lane&15); k = kt*32 + (j>>2)*16 + (lane>>4)*4 + (j&3)
__global__ __launch_bounds__(256) void prep_weights(
    const float* __restrict__ R1f, const float* __restrict__ R2f, const float* __restrict__ W2f,
    const float* __restrict__ R1b, const float* __restrict__ R2b, const float* __restrict__ W2b,
    unsigned short* __restrict__ dst)
{
  unsigned c = blockIdx.x * 256u + threadIdx.x;
  if (c >= 2359296u) return;
  unsigned reg = c / 786432u;
  unsigned cc  = c % 786432u;
  unsigned dirq = cc / 393216u;
  unsigned r = cc % 393216u;
  unsigned a = r / 6144u; r %= 6144u;
  unsigned g = r / 2048u; r %= 2048u;
  unsigned kt = r >> 6; unsigned l = r & 63u;
  unsigned col = g*1024u + a*16u + (l & 15u);
  unsigned ktbase = kt*32u, kg4 = (l >> 4)*4u;
  const float* src;
  if (reg == 0)      src = dirq ? R1b : R1f;
  else if (reg == 1) src = dirq ? R2b : R2f;
  else               src = dirq ? W2b : W2f;
  unsigned short* d = dst + (size_t)c * 8u;
  #pragma unroll
  for (int j = 0; j < 8; ++j) {
    unsigned k = ktbase + ((j >> 2) << 4) + kg4 + (j & 3);
    d[j] = f2bf(src[(size_t)k * 3072u + col]);
  }
}

// ---------------- helpers ----------------
__device__ __forceinline__ void poll_ge2(unsigned* base, int lane, int tgt, long* budget){
  if (tgt <= 0 || *budget <= 0) return;
  long it = 0;
  while (1) {
    unsigned v0 = __hip_atomic_load(base + lane,      __ATOMIC_RELAXED, __HIP_MEMORY_SCOPE_AGENT);
    unsigned v1 = __hip_atomic_load(base + 64 + lane, __ATOMIC_RELAXED, __HIP_MEMORY_SCOPE_AGENT);
    unsigned v = v0 < v1 ? v0 : v1;
    if (__all((int)v >= tgt)) return;
    if (++it > *budget) { *budget = 0; return; }   // safety valve
    __builtin_amdgcn_s_sleep(1);
  }
}
__device__ __forceinline__ bf16x8 ld_frag(const char* slot, int kt, int mt, int lane){
  const uint64_t* p = (const uint64_t*)(slot + (((size_t)(kt*2 + mt)*64 + lane) << 4));
  union { uint64_t u[2]; bf16x8 v; } f;
  f.u[0] = __hip_atomic_load((uint64_t*)p,     __ATOMIC_RELAXED, __HIP_MEMORY_SCOPE_AGENT);
  f.u[1] = __hip_atomic_load((uint64_t*)p + 1, __ATOMIC_RELAXED, __HIP_MEMORY_SCOPE_AGENT);
  return f.v;
}
// same-wave LDS transpose read: MUST be compiler-fenced against the preceding
// short stores (TBAA would otherwise allow reordering; HW LDS is in-order per wave)
__device__ __forceinline__ uint64_t lds_transpose_read(const char* p){
  asm volatile("" ::: "memory");
  __builtin_amdgcn_sched_barrier(0);
  uint64_t v; __builtin_memcpy(&v, p, 8);
  return v;
}

// ---------------- main persistent pipelined kernel ----------------
__global__ __launch_bounds__(256, 1) void enc_main(
    const int* __restrict__ tokens,
    const float* __restrict__ W1f, const float* __restrict__ W1b,
    const float* __restrict__ b1f, const float* __restrict__ b1b,
    const float* __restrict__ b2f, const float* __restrict__ b2b,
    char* __restrict__ ws, float* __restrict__ out)
{
  extern __shared__ char smem[];
  const int tid  = threadIdx.x;
  const int lane = tid & 63;
  const int wave = tid >> 6;
  const int mt   = wave >> 1;       // m-tile (batch 16-block)
  const int kh   = wave & 1;        // k-half (512)
  const int bid  = blockIdx.x;
  const int role = bid >> 6;        // 0 A_f, 1 C_f, 2 A_b, 3 C_b
  const int idx  = bid & 63;
  const int dir  = role >> 1;
  const int isC  = role & 1;
  const int u0   = idx * 16;
  const int kt0  = u0 >> 5;
  const int uh8  = ((u0 >> 4) & 1) * 8;
  const int i16  = lane & 15;
  const int lg   = lane >> 4;

  unsigned* flags = (unsigned*)(ws + FLG_OFF);
  unsigned* fA1 = flags + dir*128;          // [mtl(2)][idx(64)]
  unsigned* fC1 = flags + 256 + dir*128;
  char* hr1 = ws + HR1_OFF + (size_t)dir * 1048576;
  char* hr2 = ws + HR2_OFF + (size_t)dir * 1048576;
  const float* b1 = dir ? b1b : b1f;
  const float* b2 = dir ? b2b : b2f;
  const float* W1 = dir ? W1b : W1f;

  union FZ { uint64_t u[2]; bf16x8 v; };
  FZ fz; fz.u[0] = 0; fz.u[1] = 0;
  const bf16x8 zfrag = fz.v;

  long budget = 2000000;

  // stage recurrence weights (A: R1, C: R2)
  {
    const size_t recoff = (isC ? R2L_OFF : R1L_OFF) + (size_t)(dir*64 + idx) * 98304;
    const uint4* rs = (const uint4*)(ws + recoff);
    uint4* rd = (uint4*)(smem + SM_RECW);
    #pragma unroll
    for (int i = 0; i < 24; ++i) rd[tid + 256*i] = rs[tid + 256*i];
  }

  if (!isC) {
    // ================= stage A: layer-1 recurrence =================
    __syncthreads();
    bf16x8 hfr[16];
    #pragma unroll
    for (int q = 0; q < 16; ++q) hfr[q] = zfrag;
    float hold[4] = {0.f,0.f,0.f,0.f};
    float x1z[4], x1r[4], x1h[4];
    float b0z=0,b0r=0,b0h=0,brz=0,brr=0,brh=0;
    if (kh == 0) {
      b0z = b1[u0 + i16]; b0r = b1[1024 + u0 + i16]; b0h = b1[2048 + u0 + i16];
      brz = b1[3072 + u0 + i16]; brr = b1[4096 + u0 + i16]; brh = b1[5120 + u0 + i16];
      int tt = dir ? 511 : 0;
      #pragma unroll
      for (int r = 0; r < 4; ++r) {
        int m = mt*16 + lg*4 + r;
        int tok = tokens[m*512 + tt];
        const float* p = W1 + (size_t)tok*3072 + u0 + i16;
        x1z[r] = p[0]; x1r[r] = p[1024]; x1h[r] = p[2048];
      }
    }
    for (int t = 0; t < 512; ++t) {
      float nz[4], nr[4], nh[4];
      if (kh == 0 && t < 511) {               // prefetch next embedding slice
        int tt = dir ? (510 - t) : (t + 1);
        #pragma unroll
        for (int r = 0; r < 4; ++r) {
          int m = mt*16 + lg*4 + r;
          int tok = tokens[m*512 + tt];
          const float* p = W1 + (size_t)tok*3072 + u0 + i16;
          nz[r] = p[0]; nr[r] = p[1024]; nh[r] = p[2048];
        }
      }
      f32x4 az = {0,0,0,0}, ar = {0,0,0,0}, ah = {0,0,0,0};
      #pragma unroll
      for (int q = 0; q < 16; ++q) {
        int kt = kh*16 + q;
        bf16x8 a = hfr[q];
        az = mfma16(a, *(const bf16x8*)(smem + SM_RECW +         (kt<<10) + (lane<<4)), az);
        ar = mfma16(a, *(const bf16x8*)(smem + SM_RECW + 32768 + (kt<<10) + (lane<<4)), ar);
        ah = mfma16(a, *(const bf16x8*)(smem + SM_RECW + 65536 + (kt<<10) + (lane<<4)), ah);
      }
      __syncthreads();
      if (kh == 1) {
        f32x4* red = (f32x4*)(smem + (mt ? SM_RED1 : SM_RED0));
        red[lane] = az; red[64 + lane] = ar; red[128 + lane] = ah;
      }
      __syncthreads();
      char* h1slot = hr1 + (size_t)(t & 15) * 65536;
      if (kh == 0) {
        const f32x4* red = (const f32x4*)(smem + (mt ? SM_RED1 : SM_RED0));
        f32x4 rz = red[lane], rr4 = red[64 + lane], rh = red[128 + lane];
        #pragma unroll
        for (int r = 0; r < 4; ++r) {
          float zp = x1z[r] + b0z + az[r] + rz[r] + brz;
          float rp = x1r[r] + b0r + ar[r] + rr4[r] + brr;
          float zg = 1.f / (1.f + __expf(-zp));
          float rg = 1.f / (1.f + __expf(-rp));
          float hp = (x1h[r] + b0h) + rg * (ah[r] + rh[r] + brh);
          float e2 = __expf(-2.f * hp);
          float th = (1.f - e2) / (1.f + e2);
          float hn = zg * hold[r] + (1.f - zg) * th;
          hold[r] = hn;
          *(unsigned short*)(smem + SM_HST + ((mt*16 + lg*4 + r)*16 + i16)*2) = f2bf(hn);
        }
        // fenced same-wave LDS transpose read (see helper)
        uint64_t v = lds_transpose_read(smem + SM_HST + ((mt*16 + i16)*16 + lg*4)*2);
        if ((t & 7) == 0) poll_ge2(fC1, lane, t - 7, &budget);   // ring back-pressure (amortized)
        __hip_atomic_store((uint64_t*)(h1slot + (((size_t)(kt0*2 + mt)*64 + lane) << 4) + uh8),
                           v, __ATOMIC_RELAXED, __HIP_MEMORY_SCOPE_AGENT);
        if (lane == 0)
          __hip_atomic_store(fA1 + mt*64 + idx, (unsigned)(t + 1), __ATOMIC_RELEASE, __HIP_MEMORY_SCOPE_AGENT);
      }
      if (t < 511) {
        poll_ge2(fA1, lane, t + 1, &budget);
        #pragma unroll
        for (int q = 0; q < 16; ++q) hfr[q] = ld_frag(h1slot, kh*16 + q, mt, lane);
        if (kh == 0) {
          #pragma unroll
          for (int r = 0; r < 4; ++r) { x1z[r] = nz[r]; x1r[r] = nr[r]; x1h[r] = nh[r]; }
        }
      } else if (kh == 0) {
        #pragma unroll
        for (int r = 0; r < 4; ++r)
          out[YSZ + (size_t)dir*65536 + (size_t)(mt*16 + lg*4 + r)*2048 + u0 + i16] = hold[r];
      }
    }
  } else {
    // ================= stage C: layer-2 (x2 computed locally) =================
    bf16x8 w2z[16], w2r[16];
    {
      const size_t w2off = W2L_OFF + (size_t)(dir*64 + idx) * 98304;
      const uint4* xs = (const uint4*)(ws + w2off + 65536);   // h-gate slice -> LDS
      uint4* xd = (uint4*)(smem + SM_XWH);
      #pragma unroll
      for (int i = 0; i < 8; ++i) xd[tid + 256*i] = xs[tid + 256*i];
      const char* wb = ws + w2off;                            // z/r gate slices -> regs
      #pragma unroll
      for (int q = 0; q < 16; ++q) {
        int kt = kh*16 + q;
        w2z[q] = *(const bf16x8*)(wb +          ((size_t)(kt*64 + lane) << 4));
        w2r[q] = *(const bf16x8*)(wb + 32768 + ((size_t)(kt*64 + lane) << 4));
      }
    }
    __syncthreads();
    float hold[4] = {0.f,0.f,0.f,0.f};
    float b0z=0,b0r=0,b0h=0,brz=0,brr=0,brh=0;
    if (kh == 0) {
      b0z = b2[u0 + i16]; b0r = b2[1024 + u0 + i16]; b0h = b2[2048 + u0 + i16];
      brz = b2[3072 + u0 + i16]; brr = b2[4096 + u0 + i16]; brh = b2[5120 + u0 + i16];
    }
    for (int t = 0; t < 512; ++t) {
      // x2 part: needs h1[t] (A runs ahead -> usually no wait)
      poll_ge2(fA1, lane, t + 1, &budget);
      char* h1slot = hr1 + (size_t)(t & 15) * 65536;
      f32x4 xz = {0,0,0,0}, xr = {0,0,0,0}, xh = {0,0,0,0};
      #pragma unroll
      for (int q = 0; q < 16; ++q) {
        int kt = kh*16 + q;
        bf16x8 a = ld_frag(h1slot, kt, mt, lane);
        xz = mfma16(a, w2z[q], xz);
        xr = mfma16(a, w2r[q], xr);
        xh = mfma16(a, *(const bf16x8*)(smem + SM_XWH + (kt<<10) + (lane<<4)), xh);
      }
      // recurrence part: needs h2[t-1] (the critical self-loop)
      f32x4 az = {0,0,0,0}, ar = {0,0,0,0}, ah = {0,0,0,0};
      if (t > 0) {
        poll_ge2(fC1, lane, t, &budget);
        char* h2slot = hr2 + (size_t)((t - 1) & 15) * 65536;
        #pragma unroll
        for (int q = 0; q < 16; ++q) {
          int kt = kh*16 + q;
          bf16x8 a = ld_frag(h2slot, kt, mt, lane);
          az = mfma16(a, *(const bf16x8*)(smem + SM_RECW +         (kt<<10) + (lane<<4)), az);
          ar = mfma16(a, *(const bf16x8*)(smem + SM_RECW + 32768 + (kt<<10) + (lane<<4)), ar);
          ah = mfma16(a, *(const bf16x8*)(smem + SM_RECW + 65536 + (kt<<10) + (lane<<4)), ah);
        }
      }
      az += xz; ar += xr;
      __syncthreads();
      if (kh == 1) {
        f32x4* red = (f32x4*)(smem + (mt ? SM_RED1 : SM_RED0));
        red[lane] = az; red[64 + lane] = ar; red[128 + lane] = ah; red[192 + lane] = xh;
      }
      __syncthreads();
      if (kh == 0) {
        const f32x4* red = (const f32x4*)(smem + (mt ? SM_RED1 : SM_RED0));
        f32x4 rz = red[lane], rr4 = red[64 + lane], rh = red[128 + lane], rxh = red[192 + lane];
        #pragma unroll
        for (int r = 0; r < 4; ++r) {
          float zp = az[r] + rz[r] + b0z + brz;
          float rp = ar[r] + rr4[r] + b0r + brr;
          float zg = 1.f / (1.f + __expf(-zp));
          float rg = 1.f / (1.f + __expf(-rp));
          float hp = (xh[r] + rxh[r] + b0h) + rg * (ah[r] + rh[r] + brh);
          float e2 = __expf(-2.f * hp);
          float th = (1.f - e2) / (1.f + e2);
          float hn = zg * hold[r] + (1.f - zg) * th;
          hold[r] = hn;
          *(unsigned short*)(smem + SM_HST + ((mt*16 + lg*4 + r)*16 + i16)*2) = f2bf(hn);
        }
        char* h2slot = hr2 + (size_t)(t & 15) * 65536;
        uint64_t v = lds_transpose_read(smem + SM_HST + ((mt*16 + i16)*16 + lg*4)*2);
        __hip_atomic_store((uint64_t*)(h2slot + (((size_t)(kt0*2 + mt)*64 + lane) << 4) + uh8),
                           v, __ATOMIC_RELAXED, __HIP_MEMORY_SCOPE_AGENT);
        if (lane == 0)
          __hip_atomic_store(fC1 + mt*64 + idx, (unsigned)(t + 1), __ATOMIC_RELEASE, __HIP_MEMORY_SCOPE_AGENT);
        // outputs after the release so its vmcnt drain doesn't wait on them
        int tt = dir ? (511 - t) : t;
        #pragma unroll
        for (int r = 0; r < 4; ++r) {
          int m = mt*16 + lg*4 + r;
          out[((size_t)m*512 + tt)*2048 + dir*1024 + u0 + i16] = hold[r];
          if (t == 511)
            out[YSZ + (size_t)dir*65536 + (size_t)m*2048 + 1024 + u0 + i16] = hold[r];
        }
      }
    }
  }
}

extern "C" void kernel_launch(void* const* d_in, const int* in_sizes, int n_in,
                              void* d_out, int out_size, void* d_ws, size_t ws_size,
                              hipStream_t stream)
{
  const int*   tokens = (const int*)d_in[0];
  const float* W1f = (const float*)d_in[1];
  const float* R1f = (const float*)d_in[2];
  const float* b1f = (const float*)d_in[3];
  const float* W2f = (const float*)d_in[4];
  const float* R2f = (const float*)d_in[5];
  const float* b2f = (const float*)d_in[6];
  const float* W1b = (const float*)d_in[7];
  const float* R1b = (const float*)d_in[8];
  const float* b1b = (const float*)d_in[9];
  const float* W2b = (const float*)d_in[10];
  const float* R2b = (const float*)d_in[11];
  const float* b2b = (const float*)d_in[12];
  char* ws = (char*)d_ws;
  (void)in_sizes; (void)n_in; (void)out_size;
  if (ws_size < WS_NEED) return;

  hipMemsetAsync(ws + FLG_OFF, 0, 4096, stream);
  prep_weights<<<9216, 256, 0, stream>>>(R1f, R2f, W2f, R1b, R2b, W2b, (unsigned short*)ws);
  hipFuncSetAttribute((const void*)enc_main, hipFuncAttributeMaxDynamicSharedMemorySize, 163840);
  enc_main<<<256, 256, SM_BYTES, stream>>>(tokens, W1f, W1b, b1f, b1b, b2f, b2b, ws, (float*)d_out);
}